// Round 9
// baseline (132.742 us; speedup 1.0000x reference)
//
#include <hip/hip_runtime.h>

typedef unsigned short u16;
typedef __attribute__((ext_vector_type(8))) __bf16 bf16x8;
typedef __attribute__((ext_vector_type(4))) float f32x4;
typedef __attribute__((ext_vector_type(8))) u16 u16x8;
typedef __attribute__((ext_vector_type(4))) u16 u16x4;

#define T_SEQ 2048
#define DIM   1024
#define HDIM  64
#define WIN   128
#define XN_EL (2 * T_SEQ * DIM)   // 4194304

#define AS1 __attribute__((address_space(1)))
#define AS3 __attribute__((address_space(3)))

__device__ __forceinline__ u16 f2bf(float f) {
  union { float f; unsigned u; } v; v.f = f;
  unsigned r = v.u + 0x7fffu + ((v.u >> 16) & 1u);  // RNE
  return (u16)(r >> 16);
}
__device__ __forceinline__ float bf2f(u16 u) {
  union { unsigned u; float f; } v; v.u = ((unsigned)u) << 16; return v.f;
}
__device__ __forceinline__ void bar() {
  asm volatile("" ::: "memory");
  __builtin_amdgcn_s_barrier();
  asm volatile("" ::: "memory");
}

// ---------------- fused fp32 -> bf16 convert (x + 4 weights) -----------------
__global__ __launch_bounds__(256) void cvt_all(
    const float* __restrict__ x,  const float* __restrict__ wq,
    const float* __restrict__ wk, const float* __restrict__ wv,
    const float* __restrict__ wo, u16* __restrict__ xb, u16* __restrict__ wb) {
  const int bid = blockIdx.x;
  const float* s;
  u16* d;
  int off;
  if (bid < 2048) {
    s = x; d = xb; off = bid * 2048;
  } else {
    const int w = bid - 2048;
    const int m = w >> 9;
    s = (m == 0) ? wq : ((m == 1) ? wk : ((m == 2) ? wv : wo));
    d = wb + ((size_t)m << 20);
    off = (w & 511) * 2048;
  }
  const int i = off + threadIdx.x * 8;
  const float4* s4 = (const float4*)(s + i);
  float4 a = s4[0], b = s4[1];
  u16x8 r;
  r[0] = f2bf(a.x); r[1] = f2bf(a.y); r[2] = f2bf(a.z); r[3] = f2bf(a.w);
  r[4] = f2bf(b.x); r[5] = f2bf(b.y); r[6] = f2bf(b.z); r[7] = f2bf(b.w);
  *(u16x8*)(d + i) = r;
}

// ---------------- C = A @ B^T, 4-phase pipelined + T2 swizzle ---------------
// SPLIT=1: cols 0..2047 -> Q/K row-major (stride DIM); cols 2048..3071 -> V
// written TRANSPOSED per head: VT[b][h][d][t] at C + 2*XN_EL (8B packed).
template <int BM, int BN, int WM, int WN, int OS, int SPLIT, typename OUT_T>
__global__ __launch_bounds__(WM * WN * 64, 2) void gemm3(
    const u16* __restrict__ A, const u16* __restrict__ B,
    OUT_T* __restrict__ C, int nbm) {
  constexpr int NW = WM * WN;
  constexpr int RM = BM / WM, RN = BN / WN;
  constexpr int MF = RM / 16, NF = RN / 16;
  constexpr int MPH = MF / 4;
  constexpr int NT = DIM / 64;
  constexpr int CA = BM / 8, CB = BN / 8;
  constexpr int ANW = CA / NW;
  constexpr int BNW = CB / NW;

  __shared__ u16 As[2][BM * 64];
  __shared__ u16 Bs[2][BN * 64];

  const int tid = threadIdx.x;
  const int lane = tid & 63;
  const int wid = tid >> 6;
  const int wr = wid / WN, wc = wid % WN;
  const int c15 = lane & 15, g = lane >> 4;
  const int lr = lane >> 3;
  const int lcs = ((lane & 7) ^ lr) << 3;

  const int cpx = gridDim.x >> 3;
  const int bid = ((int)blockIdx.x & 7) * cpx + ((int)blockIdx.x >> 3);
  const int bm = bid % nbm;
  const int nb = bid / nbm;
  const u16* Ab = A + (size_t)bm * BM * DIM;
  const u16* Bb = B + (size_t)nb * BN * DIM;

  f32x4 acc[MF][NF];
#pragma unroll
  for (int m = 0; m < MF; ++m)
#pragma unroll
    for (int n = 0; n < NF; ++n) acc[m][n] = (f32x4){0.f, 0.f, 0.f, 0.f};

  auto stA = [&](int buf, int half, int k0) {
#pragma unroll
    for (int i = 0; i < ANW / 2; ++i) {
      const int c = half * (CA / 2) + wid * (ANW / 2) + i;
      __builtin_amdgcn_global_load_lds(
          (const AS1 void*)(Ab + (size_t)(c * 8 + lr) * DIM + k0 + lcs),
          (AS3 void*)(&As[buf][c * 512]), 16, 0, 0);
    }
  };
  auto stB = [&](int buf, int k0) {
#pragma unroll
    for (int i = 0; i < BNW; ++i) {
      const int c = wid * BNW + i;
      __builtin_amdgcn_global_load_lds(
          (const AS1 void*)(Bb + (size_t)(c * 8 + lr) * DIM + k0 + lcs),
          (AS3 void*)(&Bs[buf][c * 512]), 16, 0, 0);
    }
  };

  stA(0, 0, 0); stA(0, 1, 0);
  stB(0, 0); stB(1, 64);
  if constexpr (BNW == 3) asm volatile("s_waitcnt vmcnt(3)" ::: "memory");
  else                    asm volatile("s_waitcnt vmcnt(4)" ::: "memory");
  bar();

  for (int t = 0; t < NT; ++t) {
    const int buf = t & 1;
    const int k0 = t * 64;
    bf16x8 bfrag[NF][2];
#pragma unroll
    for (int p = 0; p < 4; ++p) {
      if (p == 0) {
#pragma unroll
        for (int n = 0; n < NF; ++n)
#pragma unroll
          for (int ks = 0; ks < 2; ++ks) {
            const int r = wc * RN + n * 16 + c15;
            bfrag[n][ks] = *(const bf16x8*)(
                &Bs[buf][r * 64 + ((ks * 32 + g * 8) ^ ((r & 7) << 3))]);
          }
      }
      bf16x8 af[MPH][2];
#pragma unroll
      for (int m = 0; m < MPH; ++m)
#pragma unroll
        for (int ks = 0; ks < 2; ++ks) {
          const int r = wr * RM + (p * MPH + m) * 16 + c15;
          af[m][ks] = *(const bf16x8*)(
              &As[buf][r * 64 + ((ks * 32 + g * 8) ^ ((r & 7) << 3))]);
        }
      if (p == 0) {
        if (t + 1 < NT) stA(buf ^ 1, 0, k0 + 64);
      } else if (p == 1) {
        if (t + 1 < NT) stA(buf ^ 1, 1, k0 + 64);
      } else if (p == 2) {
        if (t + 2 < NT) stB(buf, k0 + 128);
      } else {
        if (t < NT - 2) {
          if constexpr (BNW == 3) asm volatile("s_waitcnt vmcnt(3)" ::: "memory");
          else                    asm volatile("s_waitcnt vmcnt(4)" ::: "memory");
        } else {
          asm volatile("s_waitcnt vmcnt(0)" ::: "memory");
        }
      }
      bar();
      __builtin_amdgcn_s_setprio(1);
#pragma unroll
      for (int m = 0; m < MPH; ++m)
#pragma unroll
        for (int n = 0; n < NF; ++n)
#pragma unroll
          for (int ks = 0; ks < 2; ++ks)
            acc[p * MPH + m][n] = __builtin_amdgcn_mfma_f32_16x16x32_bf16(
                af[m][ks], bfrag[n][ks], acc[p * MPH + m][n], 0, 0, 0);
      __builtin_amdgcn_s_setprio(0);
      bar();
    }
  }

  // epilogue: C/D layout col=lane&15, row=(lane>>4)*4+j
#pragma unroll
  for (int m = 0; m < MF; ++m) {
    const int row0 = bm * BM + wr * RM + m * 16 + g * 4;
#pragma unroll
    for (int n = 0; n < NF; ++n) {
      const int col = nb * BN + wc * RN + n * 16 + c15;
      if constexpr (SPLIT) {
        if (col < 2048) {
#pragma unroll
          for (int j = 0; j < 4; ++j) {
            u16* dst = (u16*)C + (size_t)(col >> 10) * (size_t)XN_EL +
                       (col & 1023) + (size_t)(row0 + j) * DIM;
            *dst = f2bf(acc[m][n][j]);
          }
        } else {
          // V transposed per head: VT[(b*16+h)*64+d][t], t=row0..row0+3
          const int h = (col - 2048) >> 6, dd = (col - 2048) & 63;
          u16x4 pk;
#pragma unroll
          for (int j = 0; j < 4; ++j) pk[j] = f2bf(acc[m][n][j]);
          const size_t vidx =
              ((size_t)((row0 >> 11) * 16 + h) * 64 + dd) * T_SEQ + (row0 & 2047);
          *(u16x4*)((u16*)C + (size_t)2 * XN_EL + vidx) = pk;
        }
      } else {
#pragma unroll
        for (int j = 0; j < 4; ++j) {
          const size_t idx = (size_t)(row0 + j) * OS + col;
          if constexpr (sizeof(OUT_T) == 2) C[idx] = f2bf(acc[m][n][j]);
          else C[idx] = acc[m][n][j];
        }
      }
    }
  }
}

// ---------------- sparse flash attention, barrier-free (L2-direct K/V^T) -----
// K/V per head = 256KB each -> L2-resident. Each wave reads K fragments and
// V^T fragments DIRECTLY from global (u16x8), no LDS staging, no block
// barriers in the windowed path. Only LDS use: wave-local P transpose
// (same-wave DS ops are in-order). Fixed-base softmax; k=0 fixup.
__global__ __launch_bounds__(256) void sparse_attn(
    const u16* __restrict__ Q, const u16* __restrict__ K,
    const u16* __restrict__ VT, u16* __restrict__ AO) {
  __shared__ u16 Pl[4][16 * 72];     // 9216 B: per-wave P (windowed) / ps (global row)
  __shared__ float Pg[4][16];        // fixup transpose / red
  __shared__ float Gaux[328];        // global-row: qs[64] + rbuf[256] + pad

  const int tid = threadIdx.x;
  const int lane = tid & 63;
  const int wid = tid >> 6;
  const size_t ha = (size_t)blockIdx.z * T_SEQ * DIM + (size_t)blockIdx.y * HDIM;
  const size_t hv = ((size_t)blockIdx.z * 16 + blockIdx.y) * HDIM * T_SEQ;
  const u16* Qp = Q + ha;
  const u16* Kp = K + ha;
  const u16* Vp = VT + hv;

  if (blockIdx.x == 32) {
    // ---- global row 0 over all T keys ----
    float* qs   = Gaux;                // 64
    float* rbuf = Gaux + 64;           // 256
    float* ps   = (float*)(&Pl[0][0]); // 2048 floats = 8KB (fits 9216B)
    float* red  = (float*)Pg;          // 4

    if (tid < HDIM) qs[tid] = bf2f(Qp[tid]);
    __syncthreads();

    float lsum = 0.f;
#pragma unroll
    for (int j = 0; j < 8; ++j) {
      const int k = tid + 256 * j;
      const u16* kr = Kp + (size_t)k * DIM;
      float acc = 0.f;
#pragma unroll
      for (int d0 = 0; d0 < 8; ++d0) {
        u16x8 kv = *(const u16x8*)(kr + d0 * 8);
#pragma unroll
        for (int e = 0; e < 8; ++e) acc += qs[d0 * 8 + e] * bf2f(kv[e]);
      }
      const float p = __expf(acc * 0.125f);
      ps[k] = p;
      lsum += p;
    }
#pragma unroll
    for (int s = 1; s < 64; s <<= 1) lsum += __shfl_xor(lsum, s);
    if (lane == 0) red[wid] = lsum;
    __syncthreads();
    const float denom = red[0] + red[1] + red[2] + red[3];

    // PV: wave w handles key chunk w*512; lane d reads V^T row d (contiguous)
    const int d = tid & 63, kc = tid >> 6;
    const u16* vr = Vp + (size_t)d * T_SEQ + kc * 512;
    float facc = 0.f;
#pragma unroll 4
    for (int i = 0; i < 512; i += 8) {
      const u16x8 vv = *(const u16x8*)(vr + i);
#pragma unroll
      for (int e = 0; e < 8; ++e) facc += ps[kc * 512 + i + e] * bf2f(vv[e]);
    }
    rbuf[kc * 64 + d] = facc;
    __syncthreads();
    if (tid < HDIM) {
      const float tot = rbuf[tid] + rbuf[64 + tid] + rbuf[128 + tid] + rbuf[192 + tid];
      AO[ha + tid] = f2bf(tot / denom);
    }
    return;
  }

  // ---- windowed rows: barrier-free per-wave flash loop ----
  const int c15 = lane & 15;
  const int g = lane >> 4;
  const int q0 = blockIdx.x * 64;

  bf16x8 qf0, qf1;
  {
    const u16* qp = Qp + (size_t)(q0 + wid * 16 + c15) * DIM + g * 8;
    qf0 = *(const bf16x8*)qp;
    qf1 = *(const bf16x8*)(qp + 32);
  }

  float lrun[4] = {0.f, 0.f, 0.f, 0.f};
  f32x4 ao[4];
#pragma unroll
  for (int c = 0; c < 4; ++c) ao[c] = (f32x4){0.f, 0.f, 0.f, 0.f};

  const int klo = (q0 > WIN) ? (q0 - WIN) : 0;
  int khi = q0 + 64 + WIN;
  if (khi > T_SEQ) khi = T_SEQ;
  const int nt = (khi - klo) >> 6;

  for (int ti = 0; ti < nt; ++ti) {
    const int kt = klo + ti * 64;

    // ---- S = Q K^T : K fragments straight from global (L1/L2-hot) ----
    f32x4 s[4];
#pragma unroll
    for (int t = 0; t < 4; ++t) {
      const u16* kr = Kp + (size_t)(kt + t * 16 + c15) * DIM + g * 8;
      const bf16x8 ka = *(const bf16x8*)kr;
      const bf16x8 kb = *(const bf16x8*)(kr + 32);
      f32x4 z = (f32x4){0.f, 0.f, 0.f, 0.f};
      z = __builtin_amdgcn_mfma_f32_16x16x32_bf16(qf0, ka, z, 0, 0, 0);
      s[t] = __builtin_amdgcn_mfma_f32_16x16x32_bf16(qf1, kb, z, 0, 0, 0);
    }

    // ---- exp + P write (wave-local LDS); skip mask VALU on full tiles ----
    if (kt >= q0 - 65 && kt <= q0 + 65) {
#pragma unroll
      for (int j = 0; j < 4; ++j) {
#pragma unroll
        for (int t = 0; t < 4; ++t) {
          const float p = __expf(s[t][j] * 0.125f);
          lrun[j] += p;
          Pl[wid][(g * 4 + j) * 72 + t * 16 + c15] = f2bf(p);
        }
      }
    } else {
#pragma unroll
      for (int j = 0; j < 4; ++j) {
        const int qg = q0 + wid * 16 + g * 4 + j;
#pragma unroll
        for (int t = 0; t < 4; ++t) {
          const int kg = kt + t * 16 + c15;
          const int dd = qg - kg;
          const bool ok = (kg == 0) || (dd <= WIN && dd >= -WIN);
          const float p = ok ? __expf(s[t][j] * 0.125f) : 0.f;
          lrun[j] += p;
          Pl[wid][(g * 4 + j) * 72 + t * 16 + c15] = f2bf(p);
        }
      }
    }
    asm volatile("s_waitcnt lgkmcnt(0)" ::: "memory");

    // ---- O += P @ V : V^T fragments straight from global ----
    const bf16x8 pa0 = *(const bf16x8*)(&Pl[wid][c15 * 72 + g * 8]);
    const bf16x8 pa1 = *(const bf16x8*)(&Pl[wid][c15 * 72 + 32 + g * 8]);
#pragma unroll
    for (int c = 0; c < 4; ++c) {
      const u16* vr = Vp + (size_t)(c * 16 + c15) * T_SEQ + kt + g * 8;
      const bf16x8 va = *(const bf16x8*)vr;
      const bf16x8 vb = *(const bf16x8*)(vr + 32);
      ao[c] = __builtin_amdgcn_mfma_f32_16x16x32_bf16(pa0, va, ao[c], 0, 0, 0);
      ao[c] = __builtin_amdgcn_mfma_f32_16x16x32_bf16(pa1, vb, ao[c], 0, 0, 0);
    }
  }

  float ltot[4];
#pragma unroll
  for (int j = 0; j < 4; ++j) {
    float ls = lrun[j];
    ls += __shfl_xor(ls, 1);
    ls += __shfl_xor(ls, 2);
    ls += __shfl_xor(ls, 4);
    ls += __shfl_xor(ls, 8);
    ltot[j] = ls;
  }

  // ---- k=0 global-column fixup ----
  if (klo > 0) {
    const u16x8 qu0 = *(const u16x8*)&qf0;
    const u16x8 qu1 = *(const u16x8*)&qf1;
    const u16x8 k0a = *(const u16x8*)(Kp + g * 8);
    const u16x8 k0b = *(const u16x8*)(Kp + 32 + g * 8);
    float sg = 0.f;
#pragma unroll
    for (int e = 0; e < 8; ++e)
      sg += bf2f(qu0[e]) * bf2f(k0a[e]) + bf2f(qu1[e]) * bf2f(k0b[e]);
    sg += __shfl_xor(sg, 16);
    sg += __shfl_xor(sg, 32);
    const float pg = __expf(sg * 0.125f);
    Pg[wid][c15] = pg;
    asm volatile("s_waitcnt lgkmcnt(0)" ::: "memory");
#pragma unroll
    for (int j = 0; j < 4; ++j) {
      const float pj = Pg[wid][g * 4 + j];
      ltot[j] += pj;
#pragma unroll
      for (int c = 0; c < 4; ++c)
        ao[c][j] += pj * bf2f(Vp[(size_t)(c * 16 + c15) * T_SEQ]);  // V[0][d]
    }
  }

#pragma unroll
  for (int j = 0; j < 4; ++j) {
    const int qrow = q0 + wid * 16 + g * 4 + j;
    if (qrow == 0) continue;   // handled by the global-row block
    const float inv = 1.0f / ltot[j];
#pragma unroll
    for (int c = 0; c < 4; ++c)
      AO[ha + (size_t)qrow * DIM + c * 16 + c15] = f2bf(ao[c][j] * inv);
  }
}

// ---------------- launch -----------------------------------------------------
extern "C" void kernel_launch(void* const* d_in, const int* in_sizes, int n_in,
                              void* d_out, int out_size, void* d_ws, size_t ws_size,
                              hipStream_t stream) {
  const float* x  = (const float*)d_in[0];
  const float* Wq = (const float*)d_in[1];
  const float* Wk = (const float*)d_in[2];
  const float* Wv = (const float*)d_in[3];
  const float* Wo = (const float*)d_in[4];
  float* out = (float*)d_out;

  const int WN = DIM * DIM;

  u16* ws  = (u16*)d_ws;
  u16* xb  = ws;                      // bf16 x [4096,1024]; reused as AO
  u16* wb  = ws + (size_t)XN_EL;      // Wq,Wk,Wv,Wo bf16 contiguous
  u16* Wob = wb + (size_t)3 * WN;
  u16* Qb  = wb + (size_t)4 * WN;     // [4096,1024]
  u16* Kb  = Qb + (size_t)XN_EL;      // [4096,1024]
  u16* VTb = Qb + (size_t)2 * XN_EL;  // [32 heads][64 d][2048 t]

  cvt_all<<<4096, 256, 0, stream>>>(x, Wq, Wk, Wv, Wo, xb, wb);

  // fused QKV: 256x192 tiles, grid 256; epilogue: Q/K row-major, V transposed
  gemm3<256, 192, 2, 4, DIM, 1, u16><<<256, 512, 0, stream>>>(xb, wb, Qb, 16);

  // windowed attention (barrier-free) + embedded global-row blocks
  sparse_attn<<<dim3(33, 16, 2), 256, 0, stream>>>(Qb, Kb, VTb, xb);

  // output projection: 128x128 tiles, grid 256
  gemm3<128, 128, 2, 2, DIM, 0, float><<<256, 256, 0, stream>>>(xb, Wob, out, 32);
}

// Round 10
// 104.356 us; speedup vs baseline: 1.2720x; 1.2720x over previous
//
#include <hip/hip_runtime.h>

typedef unsigned short u16;
typedef __attribute__((ext_vector_type(8))) __bf16 bf16x8;
typedef __attribute__((ext_vector_type(4))) float f32x4;
typedef __attribute__((ext_vector_type(8))) u16 u16x8;

#define T_SEQ 2048
#define DIM   1024
#define HDIM  64
#define WIN   128
#define XN_EL (2 * T_SEQ * DIM)   // 4194304

#define AS1 __attribute__((address_space(1)))
#define AS3 __attribute__((address_space(3)))

__device__ __forceinline__ u16 f2bf(float f) {
  union { float f; unsigned u; } v; v.f = f;
  unsigned r = v.u + 0x7fffu + ((v.u >> 16) & 1u);  // RNE
  return (u16)(r >> 16);
}
__device__ __forceinline__ float bf2f(u16 u) {
  union { unsigned u; float f; } v; v.u = ((unsigned)u) << 16; return v.f;
}
__device__ __forceinline__ void bar() {
  asm volatile("" ::: "memory");
  __builtin_amdgcn_s_barrier();
  asm volatile("" ::: "memory");
}

// ---------------- fused fp32 -> bf16 convert (x + 4 weights) -----------------
__global__ __launch_bounds__(256) void cvt_all(
    const float* __restrict__ x,  const float* __restrict__ wq,
    const float* __restrict__ wk, const float* __restrict__ wv,
    const float* __restrict__ wo, u16* __restrict__ xb, u16* __restrict__ wb) {
  const int bid = blockIdx.x;
  const float* s;
  u16* d;
  int off;
  if (bid < 2048) {
    s = x; d = xb; off = bid * 2048;
  } else {
    const int w = bid - 2048;
    const int m = w >> 9;
    s = (m == 0) ? wq : ((m == 1) ? wk : ((m == 2) ? wv : wo));
    d = wb + ((size_t)m << 20);
    off = (w & 511) * 2048;
  }
  const int i = off + threadIdx.x * 8;
  const float4* s4 = (const float4*)(s + i);
  float4 a = s4[0], b = s4[1];
  u16x8 r;
  r[0] = f2bf(a.x); r[1] = f2bf(a.y); r[2] = f2bf(a.z); r[3] = f2bf(a.w);
  r[4] = f2bf(b.x); r[5] = f2bf(b.y); r[6] = f2bf(b.z); r[7] = f2bf(b.w);
  *(u16x8*)(d + i) = r;
}

// ---------------- C = A @ B^T, 4-phase pipelined + T2 swizzle ---------------
// SPLIT=1: B is the concatenated [3072,1024] weights; C points at Q-buffer,
// columns scatter to {Q, Q+XN_EL, Q+2*XN_EL} by col>>10 (row stride DIM).
template <int BM, int BN, int WM, int WN, int OS, int SPLIT, typename OUT_T>
__global__ __launch_bounds__(WM * WN * 64, 2) void gemm3(
    const u16* __restrict__ A, const u16* __restrict__ B,
    OUT_T* __restrict__ C, int nbm) {
  constexpr int NW = WM * WN;
  constexpr int RM = BM / WM, RN = BN / WN;
  constexpr int MF = RM / 16, NF = RN / 16;
  constexpr int MPH = MF / 4;
  constexpr int NT = DIM / 64;
  constexpr int CA = BM / 8, CB = BN / 8;
  constexpr int ANW = CA / NW;
  constexpr int BNW = CB / NW;

  __shared__ u16 As[2][BM * 64];
  __shared__ u16 Bs[2][BN * 64];

  const int tid = threadIdx.x;
  const int lane = tid & 63;
  const int wid = tid >> 6;
  const int wr = wid / WN, wc = wid % WN;
  const int c15 = lane & 15, g = lane >> 4;
  const int lr = lane >> 3;
  const int lcs = ((lane & 7) ^ lr) << 3;

  const int cpx = gridDim.x >> 3;
  const int bid = ((int)blockIdx.x & 7) * cpx + ((int)blockIdx.x >> 3);
  const int bm = bid % nbm;
  const int nb = bid / nbm;
  const u16* Ab = A + (size_t)bm * BM * DIM;
  const u16* Bb = B + (size_t)nb * BN * DIM;

  f32x4 acc[MF][NF];
#pragma unroll
  for (int m = 0; m < MF; ++m)
#pragma unroll
    for (int n = 0; n < NF; ++n) acc[m][n] = (f32x4){0.f, 0.f, 0.f, 0.f};

  auto stA = [&](int buf, int half, int k0) {
#pragma unroll
    for (int i = 0; i < ANW / 2; ++i) {
      const int c = half * (CA / 2) + wid * (ANW / 2) + i;
      __builtin_amdgcn_global_load_lds(
          (const AS1 void*)(Ab + (size_t)(c * 8 + lr) * DIM + k0 + lcs),
          (AS3 void*)(&As[buf][c * 512]), 16, 0, 0);
    }
  };
  auto stB = [&](int buf, int k0) {
#pragma unroll
    for (int i = 0; i < BNW; ++i) {
      const int c = wid * BNW + i;
      __builtin_amdgcn_global_load_lds(
          (const AS1 void*)(Bb + (size_t)(c * 8 + lr) * DIM + k0 + lcs),
          (AS3 void*)(&Bs[buf][c * 512]), 16, 0, 0);
    }
  };

  stA(0, 0, 0); stA(0, 1, 0);
  stB(0, 0); stB(1, 64);
  if constexpr (BNW == 3) asm volatile("s_waitcnt vmcnt(3)" ::: "memory");
  else                    asm volatile("s_waitcnt vmcnt(4)" ::: "memory");
  bar();

  for (int t = 0; t < NT; ++t) {
    const int buf = t & 1;
    const int k0 = t * 64;
    bf16x8 bfrag[NF][2];
#pragma unroll
    for (int p = 0; p < 4; ++p) {
      if (p == 0) {
#pragma unroll
        for (int n = 0; n < NF; ++n)
#pragma unroll
          for (int ks = 0; ks < 2; ++ks) {
            const int r = wc * RN + n * 16 + c15;
            bfrag[n][ks] = *(const bf16x8*)(
                &Bs[buf][r * 64 + ((ks * 32 + g * 8) ^ ((r & 7) << 3))]);
          }
      }
      bf16x8 af[MPH][2];
#pragma unroll
      for (int m = 0; m < MPH; ++m)
#pragma unroll
        for (int ks = 0; ks < 2; ++ks) {
          const int r = wr * RM + (p * MPH + m) * 16 + c15;
          af[m][ks] = *(const bf16x8*)(
              &As[buf][r * 64 + ((ks * 32 + g * 8) ^ ((r & 7) << 3))]);
        }
      if (p == 0) {
        if (t + 1 < NT) stA(buf ^ 1, 0, k0 + 64);
      } else if (p == 1) {
        if (t + 1 < NT) stA(buf ^ 1, 1, k0 + 64);
      } else if (p == 2) {
        if (t + 2 < NT) stB(buf, k0 + 128);
      } else {
        if (t < NT - 2) {
          if constexpr (BNW == 3) asm volatile("s_waitcnt vmcnt(3)" ::: "memory");
          else                    asm volatile("s_waitcnt vmcnt(4)" ::: "memory");
        } else {
          asm volatile("s_waitcnt vmcnt(0)" ::: "memory");
        }
      }
      bar();
      __builtin_amdgcn_s_setprio(1);
#pragma unroll
      for (int m = 0; m < MPH; ++m)
#pragma unroll
        for (int n = 0; n < NF; ++n)
#pragma unroll
          for (int ks = 0; ks < 2; ++ks)
            acc[p * MPH + m][n] = __builtin_amdgcn_mfma_f32_16x16x32_bf16(
                af[m][ks], bfrag[n][ks], acc[p * MPH + m][n], 0, 0, 0);
      __builtin_amdgcn_s_setprio(0);
      bar();
    }
  }

  // epilogue: C/D layout col=lane&15, row=(lane>>4)*4+j
#pragma unroll
  for (int m = 0; m < MF; ++m) {
    const int row0 = bm * BM + wr * RM + m * 16 + g * 4;
#pragma unroll
    for (int n = 0; n < NF; ++n) {
      const int col = nb * BN + wc * RN + n * 16 + c15;
#pragma unroll
      for (int j = 0; j < 4; ++j) {
        if constexpr (SPLIT) {
          u16* dst = (u16*)C + (size_t)(col >> 10) * (size_t)XN_EL +
                     (col & 1023) + (size_t)(row0 + j) * DIM;
          *dst = f2bf(acc[m][n][j]);
        } else {
          const size_t idx = (size_t)(row0 + j) * OS + col;
          if constexpr (sizeof(OUT_T) == 2) C[idx] = f2bf(acc[m][n][j]);
          else C[idx] = acc[m][n][j];
        }
      }
    }
  }
}

// ---------------- sparse flash attention, 128 q-rows per block ---------------
// Each wave owns 32 q-rows (two 16-row groups A/B sharing the per-wave P
// buffer). Reg-staged K/V prefetch -> LDS (R7 structure, best measured),
// fixed-base softmax, k=0 fixup, embedded vectorized global-row (x==16).
__global__ __launch_bounds__(256) void sparse_attn(
    const u16* __restrict__ Q, const u16* __restrict__ K,
    const u16* __restrict__ V, u16* __restrict__ AO) {
  __shared__ u16 Ks[64 * 72];      // [key][hd] pitch 72
  __shared__ u16 Vt[64 * 72];      // [hd][key^swz] pitch 72
  __shared__ u16 Pl[4][16 * 72];   // per-wave P [16 q][64 key]
  __shared__ float Pg[4][32];      // k=0 fixup transpose (2 groups)

  const int tid = threadIdx.x;
  const int lane = tid & 63;
  const int wid = tid >> 6;
  const size_t ha = (size_t)blockIdx.z * T_SEQ * DIM + (size_t)blockIdx.y * HDIM;
  const u16* Qp = Q + ha;
  const u16* Kp = K + ha;
  const u16* Vp = V + ha;

  if (blockIdx.x == 16) {
    // ---- global row 0 over all T keys (fixed-base softmax, vectorized) ----
    float* qs   = (float*)(&Pl[0][0]);  // 64 floats
    float* ps   = (float*)Ks;           // 2048 floats = 8KB (<= 9216B)
    float* rbuf = (float*)Vt;           // 2048 floats = 8KB
    float* red  = (float*)Pg;           // 4 floats

    if (tid < HDIM) qs[tid] = bf2f(Qp[tid]);
    __syncthreads();

    float lsum = 0.f;
#pragma unroll
    for (int j = 0; j < 8; ++j) {
      const int k = tid + 256 * j;
      const u16* kr = Kp + (size_t)k * DIM;
      float acc = 0.f;
#pragma unroll
      for (int d0 = 0; d0 < 8; ++d0) {
        u16x8 kv = *(const u16x8*)(kr + d0 * 8);
#pragma unroll
        for (int e = 0; e < 8; ++e) acc += qs[d0 * 8 + e] * bf2f(kv[e]);
      }
      const float p = __expf(acc * 0.125f);
      ps[k] = p;
      lsum += p;
    }
#pragma unroll
    for (int s = 1; s < 64; s <<= 1) lsum += __shfl_xor(lsum, s);
    if (lane == 0) red[wid] = lsum;
    __syncthreads();
    const float denom = red[0] + red[1] + red[2] + red[3];

    // PV: thread (kg,dg) accumulates 8 d's over 64 keys, vectorized V loads
    const int kg = tid >> 3, dg = tid & 7;
    float facc[8] = {0.f, 0.f, 0.f, 0.f, 0.f, 0.f, 0.f, 0.f};
#pragma unroll 8
    for (int i = 0; i < 64; ++i) {
      const int k = kg * 64 + i;
      const u16x8 vv = *(const u16x8*)(Vp + (size_t)k * DIM + dg * 8);
      const float p = ps[k];
#pragma unroll
      for (int e = 0; e < 8; ++e) facc[e] += p * bf2f(vv[e]);
    }
#pragma unroll
    for (int e = 0; e < 8; ++e) rbuf[kg * 64 + dg * 8 + e] = facc[e];
    __syncthreads();
    if (tid < HDIM) {
      float tot = 0.f;
#pragma unroll
      for (int k2 = 0; k2 < 32; ++k2) tot += rbuf[k2 * 64 + tid];
      AO[ha + tid] = f2bf(tot / denom);
    }
    return;
  }

  // ---- windowed rows ----
  const int c15 = lane & 15;
  const int g = lane >> 4;
  const int q0 = blockIdx.x * 128;
  const int qw = q0 + wid * 32;       // wave's first q row

  bf16x8 qA0, qA1, qB0, qB1;
  {
    const u16* qp = Qp + (size_t)(qw + c15) * DIM + g * 8;
    qA0 = *(const bf16x8*)qp;
    qA1 = *(const bf16x8*)(qp + 32);
    const u16* qp2 = qp + 16 * DIM;
    qB0 = *(const bf16x8*)qp2;
    qB1 = *(const bf16x8*)(qp2 + 32);
  }

  float lrA[4] = {0.f, 0.f, 0.f, 0.f}, lrB[4] = {0.f, 0.f, 0.f, 0.f};
  f32x4 aoA[4], aoB[4];
#pragma unroll
  for (int c = 0; c < 4; ++c) {
    aoA[c] = (f32x4){0.f, 0.f, 0.f, 0.f};
    aoB[c] = (f32x4){0.f, 0.f, 0.f, 0.f};
  }

  const int klo = (q0 > WIN) ? (q0 - WIN) : 0;
  int khi = q0 + 128 + WIN;
  if (khi > T_SEQ) khi = T_SEQ;
  const int nt = (khi - klo) >> 6;    // 4 or 6 (span always multiple of 64)

  const int srr = tid >> 2;           // key row 0..63
  const int scc = (tid & 3) * 16;     // hd col base
  const int vr = srr ^ (scc & 48);    // spread col-groups across banks

  const u16* kbase = Kp + (size_t)(klo + srr) * DIM + scc;
  const u16* vbase = Vp + (size_t)(klo + srr) * DIM + scc;
  u16x8 kp0 = *(const u16x8*)kbase;
  u16x8 kp1 = *(const u16x8*)(kbase + 8);
  u16x8 vp0 = *(const u16x8*)vbase;
  u16x8 vp1 = *(const u16x8*)(vbase + 8);

  for (int ti = 0; ti < nt; ++ti) {
    const int kt = klo + ti * 64;
    *(u16x8*)(Ks + srr * 72 + scc) = kp0;
    *(u16x8*)(Ks + srr * 72 + scc + 8) = kp1;
#pragma unroll
    for (int e = 0; e < 8; ++e) {
      Vt[(scc + e) * 72 + vr] = vp0[e];
      Vt[(scc + 8 + e) * 72 + vr] = vp1[e];
    }
    __syncthreads();

    if (ti + 1 < nt) {
      const u16* kn = kbase + (size_t)(ti + 1) * 64 * DIM;
      const u16* vn = vbase + (size_t)(ti + 1) * 64 * DIM;
      kp0 = *(const u16x8*)kn;
      kp1 = *(const u16x8*)(kn + 8);
      vp0 = *(const u16x8*)vn;
      vp1 = *(const u16x8*)(vn + 8);
    }

    auto do_group = [&](const bf16x8& qf0, const bf16x8& qf1, int r0,
                        float* lrun, f32x4* ao) {
      // ---- S = Q K^T (four 16-key groups) ----
      f32x4 s[4];
#pragma unroll
      for (int t = 0; t < 4; ++t) {
        const u16* kr = Ks + (t * 16 + c15) * 72 + g * 8;
        bf16x8 ka = *(const bf16x8*)kr;
        bf16x8 kb = *(const bf16x8*)(kr + 32);
        f32x4 z = (f32x4){0.f, 0.f, 0.f, 0.f};
        z = __builtin_amdgcn_mfma_f32_16x16x32_bf16(qf0, ka, z, 0, 0, 0);
        s[t] = __builtin_amdgcn_mfma_f32_16x16x32_bf16(qf1, kb, z, 0, 0, 0);
      }
      // ---- exp + P write; wave-uniform skip of mask VALU on full tiles ----
      if (kt >= r0 - 113 && kt <= r0 + 65) {
#pragma unroll
        for (int j = 0; j < 4; ++j) {
#pragma unroll
          for (int t = 0; t < 4; ++t) {
            const float p = __expf(s[t][j] * 0.125f);
            lrun[j] += p;
            Pl[wid][(g * 4 + j) * 72 + t * 16 + c15] = f2bf(p);
          }
        }
      } else {
#pragma unroll
        for (int j = 0; j < 4; ++j) {
          const int qg = r0 + g * 4 + j;
#pragma unroll
          for (int t = 0; t < 4; ++t) {
            const int kg = kt + t * 16 + c15;
            const int dd = qg - kg;
            const bool ok = (kg == 0) || (dd <= WIN && dd >= -WIN);
            const float p = ok ? __expf(s[t][j] * 0.125f) : 0.f;
            lrun[j] += p;
            Pl[wid][(g * 4 + j) * 72 + t * 16 + c15] = f2bf(p);
          }
        }
      }
      asm volatile("s_waitcnt lgkmcnt(0)" ::: "memory");

      // ---- O += P @ V ----
      const bf16x8 pa0 = *(const bf16x8*)(&Pl[wid][c15 * 72 + g * 8]);
      const bf16x8 pa1 = *(const bf16x8*)(&Pl[wid][c15 * 72 + 32 + g * 8]);
#pragma unroll
      for (int c = 0; c < 4; ++c) {
        const int rb = (c * 16 + c15) * 72;
        bf16x8 va = *(const bf16x8*)(Vt + rb + ((g * 8) ^ (c << 4)));
        bf16x8 vb = *(const bf16x8*)(Vt + rb + ((32 + g * 8) ^ (c << 4)));
        ao[c] = __builtin_amdgcn_mfma_f32_16x16x32_bf16(pa0, va, ao[c], 0, 0, 0);
        ao[c] = __builtin_amdgcn_mfma_f32_16x16x32_bf16(pa1, vb, ao[c], 0, 0, 0);
      }
    };

    do_group(qA0, qA1, qw, lrA, aoA);
    do_group(qB0, qB1, qw + 16, lrB, aoB);

    __syncthreads();
  }

  float ltA[4], ltB[4];
#pragma unroll
  for (int j = 0; j < 4; ++j) {
    float a = lrA[j], b = lrB[j];
    a += __shfl_xor(a, 1); b += __shfl_xor(b, 1);
    a += __shfl_xor(a, 2); b += __shfl_xor(b, 2);
    a += __shfl_xor(a, 4); b += __shfl_xor(b, 4);
    a += __shfl_xor(a, 8); b += __shfl_xor(b, 8);
    ltA[j] = a; ltB[j] = b;
  }

  // ---- k=0 global-column fixup (main loop skipped key 0 iff klo>0) ----
  if (klo > 0) {
    const u16x8 k0a = *(const u16x8*)(Kp + g * 8);
    const u16x8 k0b = *(const u16x8*)(Kp + 32 + g * 8);
    const u16x8 qa0 = *(const u16x8*)&qA0;
    const u16x8 qa1 = *(const u16x8*)&qA1;
    const u16x8 qb0 = *(const u16x8*)&qB0;
    const u16x8 qb1 = *(const u16x8*)&qB1;
    float sgA = 0.f, sgB = 0.f;
#pragma unroll
    for (int e = 0; e < 8; ++e) {
      sgA += bf2f(qa0[e]) * bf2f(k0a[e]) + bf2f(qa1[e]) * bf2f(k0b[e]);
      sgB += bf2f(qb0[e]) * bf2f(k0a[e]) + bf2f(qb1[e]) * bf2f(k0b[e]);
    }
    sgA += __shfl_xor(sgA, 16); sgA += __shfl_xor(sgA, 32);
    sgB += __shfl_xor(sgB, 16); sgB += __shfl_xor(sgB, 32);
    Pg[wid][c15] = __expf(sgA * 0.125f);
    Pg[wid][16 + c15] = __expf(sgB * 0.125f);
    asm volatile("s_waitcnt lgkmcnt(0)" ::: "memory");
#pragma unroll
    for (int j = 0; j < 4; ++j) {
      const float pA = Pg[wid][g * 4 + j];
      const float pB = Pg[wid][16 + g * 4 + j];
      ltA[j] += pA;
      ltB[j] += pB;
#pragma unroll
      for (int c = 0; c < 4; ++c) {
        const float v0 = bf2f(Vp[c * 16 + c15]);   // V[0][d]
        aoA[c][j] += pA * v0;
        aoB[c][j] += pB * v0;
      }
    }
  }

  // ---- writeout (32 rows per wave; row 0 handled by global-row block) ----
#pragma unroll
  for (int j = 0; j < 4; ++j) {
    const int qrA = qw + g * 4 + j;
    const int qrB = qrA + 16;
    const float invA = 1.0f / ltA[j];
    const float invB = 1.0f / ltB[j];
#pragma unroll
    for (int c = 0; c < 4; ++c) {
      if (qrA != 0)
        AO[ha + (size_t)qrA * DIM + c * 16 + c15] = f2bf(aoA[c][j] * invA);
      AO[ha + (size_t)qrB * DIM + c * 16 + c15] = f2bf(aoB[c][j] * invB);
    }
  }
}

// ---------------- launch -----------------------------------------------------
extern "C" void kernel_launch(void* const* d_in, const int* in_sizes, int n_in,
                              void* d_out, int out_size, void* d_ws, size_t ws_size,
                              hipStream_t stream) {
  const float* x  = (const float*)d_in[0];
  const float* Wq = (const float*)d_in[1];
  const float* Wk = (const float*)d_in[2];
  const float* Wv = (const float*)d_in[3];
  const float* Wo = (const float*)d_in[4];
  float* out = (float*)d_out;

  const int WN = DIM * DIM;

  u16* ws  = (u16*)d_ws;
  u16* xb  = ws;                      // bf16 x [4096,1024]; reused as AO
  u16* wb  = ws + (size_t)XN_EL;      // Wq,Wk,Wv,Wo bf16 contiguous
  u16* Wob = wb + (size_t)3 * WN;
  u16* Qb  = wb + (size_t)4 * WN;     // [4096,1024]
  u16* Kb  = Qb + (size_t)XN_EL;      // [4096,1024]
  u16* Vb  = Kb + (size_t)XN_EL;      // [4096,1024]

  cvt_all<<<4096, 256, 0, stream>>>(x, Wq, Wk, Wv, Wo, xb, wb);

  // fused QKV: 256x192 tiles, grid 256; epilogue splits cols into Q/K/V
  gemm3<256, 192, 2, 4, DIM, 1, u16><<<256, 512, 0, stream>>>(xb, wb, Qb, 16);

  // windowed attention (128 q-rows/block) + embedded global-row blocks
  sparse_attn<<<dim3(17, 16, 2), 256, 0, stream>>>(Qb, Kb, Vb, xb);

  // output projection: 128x128 tiles, grid 256
  gemm3<128, 128, 2, 2, DIM, 0, float><<<256, 256, 0, stream>>>(xb, Wob, out, 32);
}

// Round 11
// 102.352 us; speedup vs baseline: 1.2969x; 1.0196x over previous
//
#include <hip/hip_runtime.h>

typedef unsigned short u16;
typedef __attribute__((ext_vector_type(8))) __bf16 bf16x8;
typedef __attribute__((ext_vector_type(4))) float f32x4;
typedef __attribute__((ext_vector_type(8))) u16 u16x8;

#define T_SEQ 2048
#define DIM   1024
#define HDIM  64
#define WIN   128
#define XN_EL (2 * T_SEQ * DIM)   // 4194304

#define AS1 __attribute__((address_space(1)))
#define AS3 __attribute__((address_space(3)))

__device__ __forceinline__ u16 f2bf(float f) {
  union { float f; unsigned u; } v; v.f = f;
  unsigned r = v.u + 0x7fffu + ((v.u >> 16) & 1u);  // RNE
  return (u16)(r >> 16);
}
__device__ __forceinline__ float bf2f(u16 u) {
  union { unsigned u; float f; } v; v.u = ((unsigned)u) << 16; return v.f;
}
__device__ __forceinline__ void bar() {
  asm volatile("" ::: "memory");
  __builtin_amdgcn_s_barrier();
  asm volatile("" ::: "memory");
}

// ---------------- fused fp32 -> bf16 convert (x + 4 weights) -----------------
__global__ __launch_bounds__(256) void cvt_all(
    const float* __restrict__ x,  const float* __restrict__ wq,
    const float* __restrict__ wk, const float* __restrict__ wv,
    const float* __restrict__ wo, u16* __restrict__ xb, u16* __restrict__ wb) {
  const int bid = blockIdx.x;
  const float* s;
  u16* d;
  int off;
  if (bid < 2048) {
    s = x; d = xb; off = bid * 2048;
  } else {
    const int w = bid - 2048;
    const int m = w >> 9;
    s = (m == 0) ? wq : ((m == 1) ? wk : ((m == 2) ? wv : wo));
    d = wb + ((size_t)m << 20);
    off = (w & 511) * 2048;
  }
  const int i = off + threadIdx.x * 8;
  const float4* s4 = (const float4*)(s + i);
  float4 a = s4[0], b = s4[1];
  u16x8 r;
  r[0] = f2bf(a.x); r[1] = f2bf(a.y); r[2] = f2bf(a.z); r[3] = f2bf(a.w);
  r[4] = f2bf(b.x); r[5] = f2bf(b.y); r[6] = f2bf(b.z); r[7] = f2bf(b.w);
  *(u16x8*)(d + i) = r;
}

// ---------------- QKV GEMM: 8-phase / 2 K-tiles per iteration ---------------
// BM=256 x BN=192, 8 waves (2Mx4N), BK=64, NT=16 K-tiles.
// Per phase: {ds_read frags; stage ONE A-half (2 loads/wave) or B-third
// (1 load/wave); [p3/p7: vmcnt(3)]; bar; setprio; 12 MFMA; setprio; bar}.
// Stage ring (target dead >= 2 barriers before stage-issue; see audit):
//  p0: Ah0(t2+1)   p1: Ah1(t2+1), Bt0(t2+2)   p2: Bt1(t2+2)
//  p3: Bt2(t2+2) + vmcnt(3)  [publishes tile t2+1: exactly 3 newer loads]
//  p4: Ah0(t2+2)   p5: Ah1(t2+2), Bt0(t2+3)   p6: Bt1(t2+3)
//  p7: Bt2(t2+3) + vmcnt(3)  [publishes tile t2+2]
// Epilogue scatters cols: {Q, K, V} by col>>10 (row stride DIM).
__global__ __launch_bounds__(512, 2) void gemm8(
    const u16* __restrict__ A, const u16* __restrict__ B,
    u16* __restrict__ C, int nbm) {
  constexpr int NT = 16;
  __shared__ u16 As[2][256 * 64];
  __shared__ u16 Bs[2][192 * 64];

  const int tid = threadIdx.x;
  const int lane = tid & 63;
  const int wid = tid >> 6;
  const int wr = wid >> 2, wc = wid & 3;
  const int c15 = lane & 15, g = lane >> 4;
  const int lr = lane >> 3;
  const int lcs = ((lane & 7) ^ lr) << 3;   // inverse-swizzled source col

  const int cpx = gridDim.x >> 3;           // bijective XCD swizzle (256%8==0)
  const int bid = ((int)blockIdx.x & 7) * cpx + ((int)blockIdx.x >> 3);
  const int bm = bid % nbm;
  const int nb = bid / nbm;
  const u16* Ab = A + (size_t)bm * 256 * DIM;
  const u16* Bb = B + (size_t)nb * 192 * DIM;

  f32x4 acc[8][3];
#pragma unroll
  for (int m = 0; m < 8; ++m)
#pragma unroll
    for (int n = 0; n < 3; ++n) acc[m][n] = (f32x4){0.f, 0.f, 0.f, 0.f};

  auto stAh = [&](int buf, int half, int t) {   // one A half-tile: 2 loads/wave
    const int k0 = t * 64;
#pragma unroll
    for (int i = 0; i < 2; ++i) {
      const int c = half * 16 + wid * 2 + i;
      __builtin_amdgcn_global_load_lds(
          (const AS1 void*)(Ab + (size_t)(c * 8 + lr) * DIM + k0 + lcs),
          (AS3 void*)(&As[buf][c * 512]), 16, 0, 0);
    }
  };
  auto stBt = [&](int buf, int third, int t) {  // one B third-tile: 1 load/wave
    const int k0 = t * 64;
    const int c = third * 8 + wid;
    __builtin_amdgcn_global_load_lds(
        (const AS1 void*)(Bb + (size_t)(c * 8 + lr) * DIM + k0 + lcs),
        (AS3 void*)(&Bs[buf][c * 512]), 16, 0, 0);
  };

  // prologue: A(0), B(0), B(1); vmcnt(3) leaves only B(1) in flight.
  stAh(0, 0, 0); stAh(0, 1, 0);
  stBt(0, 0, 0); stBt(0, 1, 0); stBt(0, 2, 0);
  stBt(1, 0, 1); stBt(1, 1, 1); stBt(1, 2, 1);
  asm volatile("s_waitcnt vmcnt(3)" ::: "memory");
  bar();

  for (int t2 = 0; t2 < NT; t2 += 2) {
    bf16x8 bfrag[3][2];
#pragma unroll
    for (int p = 0; p < 8; ++p) {
      const int q = p & 3;
      const int buf = (p >> 2);            // tile t2 -> buf0, t2+1 -> buf1
      if (q == 0) {
#pragma unroll
        for (int n = 0; n < 3; ++n)
#pragma unroll
          for (int ks = 0; ks < 2; ++ks) {
            const int r = wc * 48 + n * 16 + c15;
            bfrag[n][ks] = *(const bf16x8*)(
                &Bs[buf][r * 64 + ((ks * 32 + g * 8) ^ ((r & 7) << 3))]);
          }
      }
      bf16x8 af[2][2];
#pragma unroll
      for (int m = 0; m < 2; ++m)
#pragma unroll
        for (int ks = 0; ks < 2; ++ks) {
          const int r = wr * 128 + (q * 2 + m) * 16 + c15;
          af[m][ks] = *(const bf16x8*)(
              &As[buf][r * 64 + ((ks * 32 + g * 8) ^ ((r & 7) << 3))]);
        }
      // ---- stage slot for this phase ----
      const bool s2 = (t2 + 2) < NT;       // tiles t2+2 / t2+3 exist
      const bool s3 = (t2 + 3) < NT;
      if (p == 0) {
        stAh(1, 0, t2 + 1);
      } else if (p == 1) {
        stAh(1, 1, t2 + 1);
        if (s2) stBt(0, 0, t2 + 2);
      } else if (p == 2) {
        if (s2) stBt(0, 1, t2 + 2);
      } else if (p == 3) {
        if (s2) { stBt(0, 2, t2 + 2);
                  asm volatile("s_waitcnt vmcnt(3)" ::: "memory"); }
        else    { asm volatile("s_waitcnt vmcnt(0)" ::: "memory"); }
      } else if (p == 4) {
        if (s2) stAh(0, 0, t2 + 2);
      } else if (p == 5) {
        if (s2) stAh(0, 1, t2 + 2);
        if (s3) stBt(1, 0, t2 + 3);
      } else if (p == 6) {
        if (s3) stBt(1, 1, t2 + 3);
      } else {
        if (s3) { stBt(1, 2, t2 + 3);
                  asm volatile("s_waitcnt vmcnt(3)" ::: "memory"); }
        else if (s2) { asm volatile("s_waitcnt vmcnt(0)" ::: "memory"); }
      }
      bar();
      __builtin_amdgcn_s_setprio(1);
#pragma unroll
      for (int m = 0; m < 2; ++m)
#pragma unroll
        for (int n = 0; n < 3; ++n)
#pragma unroll
          for (int ks = 0; ks < 2; ++ks)
            acc[q * 2 + m][n] = __builtin_amdgcn_mfma_f32_16x16x32_bf16(
                af[m][ks], bfrag[n][ks], acc[q * 2 + m][n], 0, 0, 0);
      __builtin_amdgcn_s_setprio(0);
      bar();
    }
  }

  // epilogue: C/D layout col=lane&15, row=(lane>>4)*4+j; split cols to Q/K/V
#pragma unroll
  for (int m = 0; m < 8; ++m) {
    const int row0 = bm * 256 + wr * 128 + m * 16 + g * 4;
#pragma unroll
    for (int n = 0; n < 3; ++n) {
      const int col = nb * 192 + wc * 48 + n * 16 + c15;
#pragma unroll
      for (int j = 0; j < 4; ++j) {
        u16* dst = C + (size_t)(col >> 10) * (size_t)XN_EL +
                   (col & 1023) + (size_t)(row0 + j) * DIM;
        *dst = f2bf(acc[m][n][j]);
      }
    }
  }
}

// ---------------- out-proj GEMM (4-phase, unchanged) -------------------------
template <int BM, int BN, int WM, int WN, int OS, typename OUT_T>
__global__ __launch_bounds__(WM * WN * 64, 2) void gemm3(
    const u16* __restrict__ A, const u16* __restrict__ B,
    OUT_T* __restrict__ C, int nbm) {
  constexpr int NW = WM * WN;
  constexpr int RM = BM / WM, RN = BN / WN;
  constexpr int MF = RM / 16, NF = RN / 16;
  constexpr int MPH = MF / 4;
  constexpr int NT = DIM / 64;
  constexpr int CA = BM / 8, CB = BN / 8;
  constexpr int ANW = CA / NW;
  constexpr int BNW = CB / NW;

  __shared__ u16 As[2][BM * 64];
  __shared__ u16 Bs[2][BN * 64];

  const int tid = threadIdx.x;
  const int lane = tid & 63;
  const int wid = tid >> 6;
  const int wr = wid / WN, wc = wid % WN;
  const int c15 = lane & 15, g = lane >> 4;
  const int lr = lane >> 3;
  const int lcs = ((lane & 7) ^ lr) << 3;

  const int cpx = gridDim.x >> 3;
  const int bid = ((int)blockIdx.x & 7) * cpx + ((int)blockIdx.x >> 3);
  const int bm = bid % nbm;
  const int nb = bid / nbm;
  const u16* Ab = A + (size_t)bm * BM * DIM;
  const u16* Bb = B + (size_t)nb * BN * DIM;

  f32x4 acc[MF][NF];
#pragma unroll
  for (int m = 0; m < MF; ++m)
#pragma unroll
    for (int n = 0; n < NF; ++n) acc[m][n] = (f32x4){0.f, 0.f, 0.f, 0.f};

  auto stA = [&](int buf, int half, int k0) {
#pragma unroll
    for (int i = 0; i < ANW / 2; ++i) {
      const int c = half * (CA / 2) + wid * (ANW / 2) + i;
      __builtin_amdgcn_global_load_lds(
          (const AS1 void*)(Ab + (size_t)(c * 8 + lr) * DIM + k0 + lcs),
          (AS3 void*)(&As[buf][c * 512]), 16, 0, 0);
    }
  };
  auto stB = [&](int buf, int k0) {
#pragma unroll
    for (int i = 0; i < BNW; ++i) {
      const int c = wid * BNW + i;
      __builtin_amdgcn_global_load_lds(
          (const AS1 void*)(Bb + (size_t)(c * 8 + lr) * DIM + k0 + lcs),
          (AS3 void*)(&Bs[buf][c * 512]), 16, 0, 0);
    }
  };

  stA(0, 0, 0); stA(0, 1, 0);
  stB(0, 0); stB(1, 64);
  asm volatile("s_waitcnt vmcnt(4)" ::: "memory");
  bar();

  for (int t = 0; t < NT; ++t) {
    const int buf = t & 1;
    const int k0 = t * 64;
    bf16x8 bfrag[NF][2];
#pragma unroll
    for (int p = 0; p < 4; ++p) {
      if (p == 0) {
#pragma unroll
        for (int n = 0; n < NF; ++n)
#pragma unroll
          for (int ks = 0; ks < 2; ++ks) {
            const int r = wc * RN + n * 16 + c15;
            bfrag[n][ks] = *(const bf16x8*)(
                &Bs[buf][r * 64 + ((ks * 32 + g * 8) ^ ((r & 7) << 3))]);
          }
      }
      bf16x8 af[MPH][2];
#pragma unroll
      for (int m = 0; m < MPH; ++m)
#pragma unroll
        for (int ks = 0; ks < 2; ++ks) {
          const int r = wr * RM + (p * MPH + m) * 16 + c15;
          af[m][ks] = *(const bf16x8*)(
              &As[buf][r * 64 + ((ks * 32 + g * 8) ^ ((r & 7) << 3))]);
        }
      if (p == 0) {
        if (t + 1 < NT) stA(buf ^ 1, 0, k0 + 64);
      } else if (p == 1) {
        if (t + 1 < NT) stA(buf ^ 1, 1, k0 + 64);
      } else if (p == 2) {
        if (t + 2 < NT) stB(buf, k0 + 128);
      } else {
        if (t < NT - 2) asm volatile("s_waitcnt vmcnt(4)" ::: "memory");
        else            asm volatile("s_waitcnt vmcnt(0)" ::: "memory");
      }
      bar();
      __builtin_amdgcn_s_setprio(1);
#pragma unroll
      for (int m = 0; m < MPH; ++m)
#pragma unroll
        for (int n = 0; n < NF; ++n)
#pragma unroll
          for (int ks = 0; ks < 2; ++ks)
            acc[p * MPH + m][n] = __builtin_amdgcn_mfma_f32_16x16x32_bf16(
                af[m][ks], bfrag[n][ks], acc[p * MPH + m][n], 0, 0, 0);
      __builtin_amdgcn_s_setprio(0);
      bar();
    }
  }

#pragma unroll
  for (int m = 0; m < MF; ++m) {
    const int row0 = bm * BM + wr * RM + m * 16 + g * 4;
#pragma unroll
    for (int n = 0; n < NF; ++n) {
      const int col = nb * BN + wc * RN + n * 16 + c15;
#pragma unroll
      for (int j = 0; j < 4; ++j) {
        const size_t idx = (size_t)(row0 + j) * OS + col;
        if constexpr (sizeof(OUT_T) == 2) C[idx] = f2bf(acc[m][n][j]);
        else C[idx] = acc[m][n][j];
      }
    }
  }
}

// ---------------- sparse flash attention, 128 q-rows per block ---------------
__global__ __launch_bounds__(256) void sparse_attn(
    const u16* __restrict__ Q, const u16* __restrict__ K,
    const u16* __restrict__ V, u16* __restrict__ AO) {
  __shared__ u16 Ks[64 * 72];
  __shared__ u16 Vt[64 * 72];
  __shared__ u16 Pl[4][16 * 72];
  __shared__ float Pg[4][32];

  const int tid = threadIdx.x;
  const int lane = tid & 63;
  const int wid = tid >> 6;
  const size_t ha = (size_t)blockIdx.z * T_SEQ * DIM + (size_t)blockIdx.y * HDIM;
  const u16* Qp = Q + ha;
  const u16* Kp = K + ha;
  const u16* Vp = V + ha;

  if (blockIdx.x == 16) {
    float* qs   = (float*)(&Pl[0][0]);
    float* ps   = (float*)Ks;
    float* rbuf = (float*)Vt;
    float* red  = (float*)Pg;

    if (tid < HDIM) qs[tid] = bf2f(Qp[tid]);
    __syncthreads();

    float lsum = 0.f;
#pragma unroll
    for (int j = 0; j < 8; ++j) {
      const int k = tid + 256 * j;
      const u16* kr = Kp + (size_t)k * DIM;
      float acc = 0.f;
#pragma unroll
      for (int d0 = 0; d0 < 8; ++d0) {
        u16x8 kv = *(const u16x8*)(kr + d0 * 8);
#pragma unroll
        for (int e = 0; e < 8; ++e) acc += qs[d0 * 8 + e] * bf2f(kv[e]);
      }
      const float p = __expf(acc * 0.125f);
      ps[k] = p;
      lsum += p;
    }
#pragma unroll
    for (int s = 1; s < 64; s <<= 1) lsum += __shfl_xor(lsum, s);
    if (lane == 0) red[wid] = lsum;
    __syncthreads();
    const float denom = red[0] + red[1] + red[2] + red[3];

    const int kg = tid >> 3, dg = tid & 7;
    float facc[8] = {0.f, 0.f, 0.f, 0.f, 0.f, 0.f, 0.f, 0.f};
#pragma unroll 8
    for (int i = 0; i < 64; ++i) {
      const int k = kg * 64 + i;
      const u16x8 vv = *(const u16x8*)(Vp + (size_t)k * DIM + dg * 8);
      const float p = ps[k];
#pragma unroll
      for (int e = 0; e < 8; ++e) facc[e] += p * bf2f(vv[e]);
    }
#pragma unroll
    for (int e = 0; e < 8; ++e) rbuf[kg * 64 + dg * 8 + e] = facc[e];
    __syncthreads();
    if (tid < HDIM) {
      float tot = 0.f;
#pragma unroll
      for (int k2 = 0; k2 < 32; ++k2) tot += rbuf[k2 * 64 + tid];
      AO[ha + tid] = f2bf(tot / denom);
    }
    return;
  }

  const int c15 = lane & 15;
  const int g = lane >> 4;
  const int q0 = blockIdx.x * 128;
  const int qw = q0 + wid * 32;

  bf16x8 qA0, qA1, qB0, qB1;
  {
    const u16* qp = Qp + (size_t)(qw + c15) * DIM + g * 8;
    qA0 = *(const bf16x8*)qp;
    qA1 = *(const bf16x8*)(qp + 32);
    const u16* qp2 = qp + 16 * DIM;
    qB0 = *(const bf16x8*)qp2;
    qB1 = *(const bf16x8*)(qp2 + 32);
  }

  float lrA[4] = {0.f, 0.f, 0.f, 0.f}, lrB[4] = {0.f, 0.f, 0.f, 0.f};
  f32x4 aoA[4], aoB[4];
#pragma unroll
  for (int c = 0; c < 4; ++c) {
    aoA[c] = (f32x4){0.f, 0.f, 0.f, 0.f};
    aoB[c] = (f32x4){0.f, 0.f, 0.f, 0.f};
  }

  const int klo = (q0 > WIN) ? (q0 - WIN) : 0;
  int khi = q0 + 128 + WIN;
  if (khi > T_SEQ) khi = T_SEQ;
  const int nt = (khi - klo) >> 6;

  const int srr = tid >> 2;
  const int scc = (tid & 3) * 16;
  const int vr = srr ^ (scc & 48);

  const u16* kbase = Kp + (size_t)(klo + srr) * DIM + scc;
  const u16* vbase = Vp + (size_t)(klo + srr) * DIM + scc;
  u16x8 kp0 = *(const u16x8*)kbase;
  u16x8 kp1 = *(const u16x8*)(kbase + 8);
  u16x8 vp0 = *(const u16x8*)vbase;
  u16x8 vp1 = *(const u16x8*)(vbase + 8);

  for (int ti = 0; ti < nt; ++ti) {
    const int kt = klo + ti * 64;
    *(u16x8*)(Ks + srr * 72 + scc) = kp0;
    *(u16x8*)(Ks + srr * 72 + scc + 8) = kp1;
#pragma unroll
    for (int e = 0; e < 8; ++e) {
      Vt[(scc + e) * 72 + vr] = vp0[e];
      Vt[(scc + 8 + e) * 72 + vr] = vp1[e];
    }
    __syncthreads();

    if (ti + 1 < nt) {
      const u16* kn = kbase + (size_t)(ti + 1) * 64 * DIM;
      const u16* vn = vbase + (size_t)(ti + 1) * 64 * DIM;
      kp0 = *(const u16x8*)kn;
      kp1 = *(const u16x8*)(kn + 8);
      vp0 = *(const u16x8*)vn;
      vp1 = *(const u16x8*)(vn + 8);
    }

    auto do_group = [&](const bf16x8& qf0, const bf16x8& qf1, int r0,
                        float* lrun, f32x4* ao) {
      f32x4 s[4];
#pragma unroll
      for (int t = 0; t < 4; ++t) {
        const u16* kr = Ks + (t * 16 + c15) * 72 + g * 8;
        bf16x8 ka = *(const bf16x8*)kr;
        bf16x8 kb = *(const bf16x8*)(kr + 32);
        f32x4 z = (f32x4){0.f, 0.f, 0.f, 0.f};
        z = __builtin_amdgcn_mfma_f32_16x16x32_bf16(qf0, ka, z, 0, 0, 0);
        s[t] = __builtin_amdgcn_mfma_f32_16x16x32_bf16(qf1, kb, z, 0, 0, 0);
      }
      if (kt >= r0 - 113 && kt <= r0 + 65) {
#pragma unroll
        for (int j = 0; j < 4; ++j) {
#pragma unroll
          for (int t = 0; t < 4; ++t) {
            const float p = __expf(s[t][j] * 0.125f);
            lrun[j] += p;
            Pl[wid][(g * 4 + j) * 72 + t * 16 + c15] = f2bf(p);
          }
        }
      } else {
#pragma unroll
        for (int j = 0; j < 4; ++j) {
          const int qg = r0 + g * 4 + j;
#pragma unroll
          for (int t = 0; t < 4; ++t) {
            const int kg = kt + t * 16 + c15;
            const int dd = qg - kg;
            const bool ok = (kg == 0) || (dd <= WIN && dd >= -WIN);
            const float p = ok ? __expf(s[t][j] * 0.125f) : 0.f;
            lrun[j] += p;
            Pl[wid][(g * 4 + j) * 72 + t * 16 + c15] = f2bf(p);
          }
        }
      }
      asm volatile("s_waitcnt lgkmcnt(0)" ::: "memory");

      const bf16x8 pa0 = *(const bf16x8*)(&Pl[wid][c15 * 72 + g * 8]);
      const bf16x8 pa1 = *(const bf16x8*)(&Pl[wid][c15 * 72 + 32 + g * 8]);
#pragma unroll
      for (int c = 0; c < 4; ++c) {
        const int rb = (c * 16 + c15) * 72;
        bf16x8 va = *(const bf16x8*)(Vt + rb + ((g * 8) ^ (c << 4)));
        bf16x8 vb = *(const bf16x8*)(Vt + rb + ((32 + g * 8) ^ (c << 4)));
        ao[c] = __builtin_amdgcn_mfma_f32_16x16x32_bf16(pa0, va, ao[c], 0, 0, 0);
        ao[c] = __builtin_amdgcn_mfma_f32_16x16x32_bf16(pa1, vb, ao[c], 0, 0, 0);
      }
    };

    do_group(qA0, qA1, qw, lrA, aoA);
    do_group(qB0, qB1, qw + 16, lrB, aoB);

    __syncthreads();
  }

  float ltA[4], ltB[4];
#pragma unroll
  for (int j = 0; j < 4; ++j) {
    float a = lrA[j], b = lrB[j];
    a += __shfl_xor(a, 1); b += __shfl_xor(b, 1);
    a += __shfl_xor(a, 2); b += __shfl_xor(b, 2);
    a += __shfl_xor(a, 4); b += __shfl_xor(b, 4);
    a += __shfl_xor(a, 8); b += __shfl_xor(b, 8);
    ltA[j] = a; ltB[j] = b;
  }

  if (klo > 0) {
    const u16x8 k0a = *(const u16x8*)(Kp + g * 8);
    const u16x8 k0b = *(const u16x8*)(Kp + 32 + g * 8);
    const u16x8 qa0 = *(const u16x8*)&qA0;
    const u16x8 qa1 = *(const u16x8*)&qA1;
    const u16x8 qb0 = *(const u16x8*)&qB0;
    const u16x8 qb1 = *(const u16x8*)&qB1;
    float sgA = 0.f, sgB = 0.f;
#pragma unroll
    for (int e = 0; e < 8; ++e) {
      sgA += bf2f(qa0[e]) * bf2f(k0a[e]) + bf2f(qa1[e]) * bf2f(k0b[e]);
      sgB += bf2f(qb0[e]) * bf2f(k0a[e]) + bf2f(qb1[e]) * bf2f(k0b[e]);
    }
    sgA += __shfl_xor(sgA, 16); sgA += __shfl_xor(sgA, 32);
    sgB += __shfl_xor(sgB, 16); sgB += __shfl_xor(sgB, 32);
    Pg[wid][c15] = __expf(sgA * 0.125f);
    Pg[wid][16 + c15] = __expf(sgB * 0.125f);
    asm volatile("s_waitcnt lgkmcnt(0)" ::: "memory");
#pragma unroll
    for (int j = 0; j < 4; ++j) {
      const float pA = Pg[wid][g * 4 + j];
      const float pB = Pg[wid][16 + g * 4 + j];
      ltA[j] += pA;
      ltB[j] += pB;
#pragma unroll
      for (int c = 0; c < 4; ++c) {
        const float v0 = bf2f(Vp[c * 16 + c15]);
        aoA[c][j] += pA * v0;
        aoB[c][j] += pB * v0;
      }
    }
  }

#pragma unroll
  for (int j = 0; j < 4; ++j) {
    const int qrA = qw + g * 4 + j;
    const int qrB = qrA + 16;
    const float invA = 1.0f / ltA[j];
    const float invB = 1.0f / ltB[j];
#pragma unroll
    for (int c = 0; c < 4; ++c) {
      if (qrA != 0)
        AO[ha + (size_t)qrA * DIM + c * 16 + c15] = f2bf(aoA[c][j] * invA);
      AO[ha + (size_t)qrB * DIM + c * 16 + c15] = f2bf(aoB[c][j] * invB);
    }
  }
}

// ---------------- launch -----------------------------------------------------
extern "C" void kernel_launch(void* const* d_in, const int* in_sizes, int n_in,
                              void* d_out, int out_size, void* d_ws, size_t ws_size,
                              hipStream_t stream) {
  const float* x  = (const float*)d_in[0];
  const float* Wq = (const float*)d_in[1];
  const float* Wk = (const float*)d_in[2];
  const float* Wv = (const float*)d_in[3];
  const float* Wo = (const float*)d_in[4];
  float* out = (float*)d_out;

  const int WN = DIM * DIM;

  u16* ws  = (u16*)d_ws;
  u16* xb  = ws;                      // bf16 x [4096,1024]; reused as AO
  u16* wb  = ws + (size_t)XN_EL;      // Wq,Wk,Wv,Wo bf16 contiguous
  u16* Wob = wb + (size_t)3 * WN;
  u16* Qb  = wb + (size_t)4 * WN;     // [4096,1024]
  u16* Kb  = Qb + (size_t)XN_EL;      // [4096,1024]
  u16* Vb  = Kb + (size_t)XN_EL;      // [4096,1024]

  cvt_all<<<4096, 256, 0, stream>>>(x, Wq, Wk, Wv, Wo, xb, wb);

  // fused QKV: 256x192 tiles, 8-phase schedule, grid 16*16 = 256
  gemm8<<<256, 512, 0, stream>>>(xb, wb, Qb, 16);

  // windowed attention (128 q-rows/block) + embedded global-row blocks
  sparse_attn<<<dim3(17, 16, 2), 256, 0, stream>>>(Qb, Kb, Vb, xb);

  // output projection: 128x128 tiles, grid 256
  gemm3<128, 128, 2, 2, DIM, float><<<256, 256, 0, stream>>>(xb, Wob, out, 32);
}